// Round 8
// baseline (593.854 us; speedup 1.0000x reference)
//
#include <hip/hip_runtime.h>

// N=100000 nodes, M=800000 edges, F_IN=64, F_E=16, H=64, T_NODE=2, T_EDGE=3.
// score == softmax over singleton axis == 1.0 exactly, so h3/h4/num are dead:
//   out[n] = h1[n] + sum_{e: dst=n} ( h2[src_e] + ef_e . W5[t_e] + b5[t_e] )
//
// R8: bucket-CSR with ZERO global atomics.
//   bucket = dst>>5 (32 dsts/bucket). K1: per-block LDS hist -> table rows.
//   K2a/b/c: column sums -> prefix -> per-(block,bucket) offsets (all tiny).
//   K3: gemm (MFMA, both types) || bin-scatter (LDS ds_add_rtn cursors,
//       fire-and-forget 8B stores). K4: block-per-bucket gather: coalesced
//       edge reads, LDS fp32 accumulation (h2 + per-type ef sums + counts),
//       per-dst 51x64 matvec, single-writer plain out[d] += r. No fixup.

#define ABLK 64     // pass-A blocks (rows of the offset table)
#define TS   3200   // table row stride (>= NB = ceil(N/32) = 3125)

typedef __attribute__((ext_vector_type(8))) short short8;
typedef __attribute__((ext_vector_type(4))) float f32x4;

__device__ __forceinline__ float b2f(unsigned short u) {
    union { unsigned v; float f; } x; x.v = ((unsigned)u) << 16; return x.f;
}
__device__ __forceinline__ unsigned short f2b(float f) {
    union { float f; unsigned v; } x; x.f = f;
    unsigned u = x.v;
    unsigned r = (u + 0x7FFFu + ((u >> 16) & 1u)) >> 16;
    return (unsigned short)r;
}

// ---------------- K1: per-block bucket histogram ----------------
__global__ __launch_bounds__(256) void k_hist(
    const int* __restrict__ edst, int* __restrict__ table,
    int M, int NB, int epb)
{
    __shared__ int h[TS];
    int tid = threadIdx.x;
    for (int t = tid; t < TS; t += 256) h[t] = 0;
    __syncthreads();
    int base = blockIdx.x * epb;
    for (int i = tid; i < epb; i += 256) {
        int e = base + i;
        if (e < M) atomicAdd(&h[edst[e] >> 5], 1);
    }
    __syncthreads();
    for (int t = tid; t < NB; t += 256) table[blockIdx.x * TS + t] = h[t];
}

// ---------------- K2a: column sums over ABLK rows ----------------
__global__ __launch_bounds__(256) void k_colsum(
    const int* __restrict__ table, int* __restrict__ totals, int NB)
{
    int t = blockIdx.x * 256 + threadIdx.x;
    if (t >= NB) return;
    int s = 0;
    for (int j = 0; j < ABLK; ++j) s += table[j * TS + t];
    totals[t] = s;
}

// ---------------- K2b: single-block exclusive prefix ----------------
__global__ __launch_bounds__(256) void k_prefix(
    const int* __restrict__ totals, int* __restrict__ starts, int NB, int M)
{
    __shared__ int ps[256];
    int tid = threadIdx.x;
    int per = (NB + 255) / 256;
    int lo = tid * per, hi = min(lo + per, NB);
    int s = 0;
    for (int i = lo; i < hi; ++i) s += totals[i];
    ps[tid] = s;
    __syncthreads();
    int run = s;
    for (int off = 1; off < 256; off <<= 1) {
        int tmp = (tid >= off) ? ps[tid - off] : 0;
        __syncthreads();
        run += tmp;
        ps[tid] = run;
        __syncthreads();
    }
    int r = run - s;   // exclusive prefix of my chunk
    for (int i = lo; i < hi; ++i) { starts[i] = r; r += totals[i]; }
    if (tid == 255) starts[NB] = M;
}

// ---------------- K2c: rewrite table rows to per-(block,bucket) bases -------
__global__ __launch_bounds__(256) void k_offsets(
    int* __restrict__ table, const int* __restrict__ starts, int NB)
{
    int t = blockIdx.x * 256 + threadIdx.x;
    if (t >= NB) return;
    int run = starts[t];
    for (int j = 0; j < ABLK; ++j) {
        int v = table[j * TS + t];
        table[j * TS + t] = run;
        run += v;
    }
}

// ---------------- K3: bin-scatter (blocks 0..ABLK) || MFMA gemm -------------
__global__ __launch_bounds__(256) void k3_gemm_binscatter(
    const float* __restrict__ x, const int* __restrict__ nt,
    const float* __restrict__ W1, const float* __restrict__ b1,
    const float* __restrict__ W2, const float* __restrict__ b2,
    const int* __restrict__ esrc, const int* __restrict__ edst,
    const int* __restrict__ etype,
    const int* __restrict__ table, int2* __restrict__ rec,
    float* __restrict__ out, unsigned short* __restrict__ h2b,
    int N, int M, int NB, int epb)
{
    // union-aliased LDS: gemm needs 55808 B; scatter needs TS*4 = 12800 B
    __shared__ __align__(16) char smem[55808];

    int tid = threadIdx.x;

    if (blockIdx.x < ABLK) {
        // ---------------- bin-scatter path ----------------
        int* loc = (int*)smem;
        int b = blockIdx.x;
        for (int t = tid; t < NB; t += 256) loc[t] = table[b * TS + t];
        __syncthreads();
        int base = b * epb;
        for (int i = tid; i < epb; i += 256) {
            int e = base + i;
            if (e >= M) break;
            int d = edst[e];
            int bkt = d >> 5, dloc = d & 31;
            int pos = atomicAdd(&loc[bkt], 1);          // LDS cursor
            int packed = esrc[e] | (etype[e] << 17) | (dloc << 19);
            rec[pos] = make_int2(packed, e);            // fire-and-forget
        }
        return;
    }

    // ---------------- gemm path: 128 rows x 64 h, 4 weight mats -------------
    unsigned short* sx = (unsigned short*)smem;               // 128*72 shorts
    unsigned short* sw = (unsigned short*)(smem + 18432);     // 4*64*72 shorts
    int* snt = (int*)(smem + 55296);                          // 128 ints

    int rowbase = (blockIdx.x - ABLK) * 128;

    const float* Wm[4] = { W1, W1 + 4096, W2, W2 + 4096 };    // [k][n] fp32
#pragma unroll
    for (int j = 0; j < 4; ++j) {
        int k  = (tid >> 4) + j * 16;
        int n4 = (tid & 15) * 4;
#pragma unroll
        for (int mm = 0; mm < 4; ++mm) {
            float4 wv = *(const float4*)&Wm[mm][k * 64 + n4];
            sw[mm * 4608 + (n4 + 0) * 72 + k] = f2b(wv.x);
            sw[mm * 4608 + (n4 + 1) * 72 + k] = f2b(wv.y);
            sw[mm * 4608 + (n4 + 2) * 72 + k] = f2b(wv.z);
            sw[mm * 4608 + (n4 + 3) * 72 + k] = f2b(wv.w);
        }
    }

    if (tid < 128) {
        int r = rowbase + tid;
        snt[tid] = (r < N) ? nt[r] : 0;
    }

    int fr = (tid & 15) * 4;
    int ir = tid >> 4;
#pragma unroll
    for (int it = 0; it < 8; ++it) {
        int i = it * 16 + ir;
        int r = rowbase + i;
        float4 v = make_float4(0.f, 0.f, 0.f, 0.f);
        if (r < N) v = *(const float4*)&x[(size_t)r * 64 + fr];
        ushort4 p;
        p.x = f2b(v.x); p.y = f2b(v.y); p.z = f2b(v.z); p.w = f2b(v.w);
        *(ushort4*)&sx[i * 72 + fr] = p;
    }
    __syncthreads();

    int lane = tid & 63;
    int wid  = tid >> 6;
    int q    = lane >> 4;
    int cc   = lane & 15;
    int m0   = wid * 32;

    f32x4 acc[4][2][4];   // [mat][s][t]
#pragma unroll
    for (int mm = 0; mm < 4; ++mm)
#pragma unroll
        for (int s = 0; s < 2; ++s)
#pragma unroll
            for (int t = 0; t < 4; ++t)
                acc[mm][s][t] = (f32x4){0.f, 0.f, 0.f, 0.f};

#pragma unroll
    for (int k0 = 0; k0 < 64; k0 += 32) {
        int ko = k0 + q * 8;
        short8 af0 = *(short8*)&sx[(m0 + cc) * 72 + ko];
        short8 af1 = *(short8*)&sx[(m0 + 16 + cc) * 72 + ko];
#pragma unroll
        for (int mm = 0; mm < 4; ++mm)
#pragma unroll
            for (int t = 0; t < 4; ++t) {
                short8 bf = *(short8*)&sw[mm * 4608 + (t * 16 + cc) * 72 + ko];
                acc[mm][0][t] = __builtin_amdgcn_mfma_f32_16x16x32_bf16(
                    af0, bf, acc[mm][0][t], 0, 0, 0);
                acc[mm][1][t] = __builtin_amdgcn_mfma_f32_16x16x32_bf16(
                    af1, bf, acc[mm][1][t], 0, 0, 0);
            }
    }

    float b1v[2][4], b2v[2][4];
#pragma unroll
    for (int ty = 0; ty < 2; ++ty)
#pragma unroll
        for (int t = 0; t < 4; ++t) {
            b1v[ty][t] = b1[ty * 64 + t * 16 + cc];
            b2v[ty][t] = b2[ty * 64 + t * 16 + cc];
        }

    // C/D layout: col = lane&15, row = quad*4 + reg
#pragma unroll
    for (int s = 0; s < 2; ++s)
#pragma unroll
        for (int reg = 0; reg < 4; ++reg) {
            int rl = m0 + s * 16 + q * 4 + reg;
            int r = rowbase + rl;
            if (r < N) {
                int ty = snt[rl];
#pragma unroll
                for (int t = 0; t < 4; ++t) {
                    float v1 = (ty ? acc[1][s][t][reg] : acc[0][s][t][reg])
                               + b1v[ty][t];
                    float v2 = (ty ? acc[3][s][t][reg] : acc[2][s][t][reg])
                               + b2v[ty][t];
                    out[(size_t)r * 64 + t * 16 + cc] = v1;
                    h2b[(size_t)r * 64 + t * 16 + cc] = f2b(v2);
                }
            }
        }
}

// ---------------- K4: block-per-bucket gather ----------------
// Per edge: all lanes ds_add h2b[src][lane] into sH[dloc]; lanes 0..50 ds_add
// the masked per-type ef value / count into sS[dloc]. Epilogue: per dst,
// r = sH + sum_j sS[j]*Wcat[j][lane]; out[d] += r (single writer, no atomic).
__global__ __launch_bounds__(256) void k4_gather(
    const float* __restrict__ ef, const int2* __restrict__ rec,
    const int* __restrict__ starts,
    const float* __restrict__ W5, const float* __restrict__ b5,
    const unsigned short* __restrict__ h2b, float* __restrict__ out, int N)
{
    __shared__ float sW[3264];      // W5 [t*16+f][h] then b5 [t][h]
    __shared__ float sH[32 * 64];   // per-dst h2 sums
    __shared__ float sS[32 * 52];   // per-dst [48 ef sums | 3 counts | pad]

    int tid = threadIdx.x;
    for (int k = tid; k < 816; k += 256)
        ((float4*)sW)[k] = (k < 768) ? ((const float4*)W5)[k]
                                     : ((const float4*)b5)[k - 768];
    for (int k = tid; k < 2048; k += 256) sH[k] = 0.f;
    for (int k = tid; k < 1664; k += 256) sS[k] = 0.f;
    __syncthreads();

    int b = blockIdx.x;
    int beg = starts[b];
    int nE = starts[b + 1] - beg;

    int lane = tid & 63;
    int wid  = tid >> 6;
    int qq = (nE + 3) >> 2;
    int lo = wid * qq, hi = min(lo + qq, nE);

    int myf = lane & 15;
    bool sLane = lane < 51;
    int myt = (lane < 48) ? (lane >> 4) : (lane - 48);

    for (int i = lo; i < hi; i += 8) {
        int nrem = hi - i;
        int2 r[8];
#pragma unroll
        for (int j = 0; j < 8; ++j) {
            int ij = i + j;
            ij = (ij < hi) ? ij : (hi - 1);     // clamp; masked below
            r[j] = rec[beg + ij];
        }
        float hv[8], ev[8];
#pragma unroll
        for (int j = 0; j < 8; ++j) {
            int s = r[j].x & 0x1FFFF;
            hv[j] = b2f(h2b[(size_t)s * 64 + lane]);
            ev[j] = ef[(size_t)r[j].y * 16 + myf];
        }
#pragma unroll
        for (int j = 0; j < 8; ++j) {
            bool ok = j < nrem;                 // wave-uniform
            int t  = (r[j].x >> 17) & 3;
            int dl = (r[j].x >> 19) & 31;
            if (ok) {
                atomicAdd(&sH[dl * 64 + lane], hv[j]);
                float v = (lane < 48) ? ev[j] : 1.0f;
                if (sLane && t == myt) atomicAdd(&sS[dl * 52 + lane], v);
            }
        }
    }
    __syncthreads();

    // 8 dsts per wave
    for (int dl = wid * 8; dl < wid * 8 + 8; ++dl) {
        int d = b * 32 + dl;
        if (d >= N) break;
        float rr = sH[dl * 64 + lane];
#pragma unroll
        for (int j = 0; j < 48; ++j)
            rr = fmaf(sS[dl * 52 + j], sW[j * 64 + lane], rr);
#pragma unroll
        for (int t = 0; t < 3; ++t)
            rr = fmaf(sS[dl * 52 + 48 + t], sW[3072 + t * 64 + lane], rr);
        out[(size_t)d * 64 + lane] += rr;       // single writer per d
    }
}

extern "C" void kernel_launch(void* const* d_in, const int* in_sizes, int n_in,
                              void* d_out, int out_size, void* d_ws, size_t ws_size,
                              hipStream_t stream) {
    const float* x  = (const float*)d_in[0];
    const float* ef = (const float*)d_in[1];
    const int* nt   = (const int*)d_in[2];
    const int* es   = (const int*)d_in[3];
    const int* ed   = (const int*)d_in[4];
    const int* et   = (const int*)d_in[5];
    const float* W1 = (const float*)d_in[6];
    const float* b1 = (const float*)d_in[7];
    const float* W2 = (const float*)d_in[8];
    const float* b2 = (const float*)d_in[9];
    // d_in[10..13] = W3,b3,W4,b4 dead (score == 1.0)
    const float* W5 = (const float*)d_in[14];
    const float* b5 = (const float*)d_in[15];

    int N = in_sizes[2];
    int M = in_sizes[3];
    int NB = (N + 31) >> 5;            // 3125 buckets (must be <= TS)
    int epb = (M + ABLK - 1) / ABLK;   // edges per pass-A block

    char* w = (char*)d_ws;
    size_t off = 0;
    unsigned short* h2b = (unsigned short*)(w + off); off += (size_t)N * 64 * 2;
    off = (off + 255) & ~(size_t)255;
    int2* rec   = (int2*)(w + off); off += (size_t)M * 8;
    off = (off + 255) & ~(size_t)255;
    int* table  = (int*)(w + off);  off += (size_t)ABLK * TS * 4;
    int* totals = (int*)(w + off);  off += (size_t)(NB + 64) * 4;
    int* starts = (int*)(w + off);  off += (size_t)(NB + 64) * 4;

    float* out = (float*)d_out;

    // no memsets needed: every consumed word is produced each launch
    k_hist<<<ABLK, 256, 0, stream>>>(ed, table, M, NB, epb);

    int cb = (NB + 255) / 256;
    k_colsum<<<cb, 256, 0, stream>>>(table, totals, NB);
    k_prefix<<<1, 256, 0, stream>>>(totals, starts, NB, M);
    k_offsets<<<cb, 256, 0, stream>>>(table, starts, NB);

    int gemmBlocks = (N + 127) / 128;
    k3_gemm_binscatter<<<ABLK + gemmBlocks, 256, 0, stream>>>(
        x, nt, W1, b1, W2, b2, es, ed, et, table, rec, out, h2b,
        N, M, NB, epb);

    k4_gather<<<NB, 256, 0, stream>>>(ef, rec, starts, W5, b5, h2b, out, N);
}